// Round 1
// baseline (172.169 us; speedup 1.0000x reference)
//
#include <hip/hip_runtime.h>

typedef __bf16 bf16_t;
typedef bf16_t bf16x8 __attribute__((ext_vector_type(8)));
typedef bf16_t bf16x4 __attribute__((ext_vector_type(4)));
typedef float f32x4 __attribute__((ext_vector_type(4)));

__device__ __forceinline__ f32x4 mfma16(bf16x8 a, bf16x8 b, f32x4 c) {
  return __builtin_amdgcn_mfma_f32_16x16x32_bf16(a, b, c, 0, 0, 0);
}

__device__ __forceinline__ void gload16(const bf16_t* g, bf16_t* l) {
  __builtin_amdgcn_global_load_lds(
      (const __attribute__((address_space(1))) void*)g,
      (__attribute__((address_space(3))) void*)l, 16, 0, 0);
}

// ---------------- convert f32 -> bf16 (vectorized) ----------------
__global__ void convert_kernel(const float* __restrict__ in, bf16_t* __restrict__ out, int n4) {
  int i = blockIdx.x * blockDim.x + threadIdx.x;
  if (i < n4) {
    float4 v = ((const float4*)in)[i];
    bf16x4 o;
    o[0] = (bf16_t)v.x; o[1] = (bf16_t)v.y; o[2] = (bf16_t)v.z; o[3] = (bf16_t)v.w;
    *(bf16x4*)&out[(size_t)i * 4] = o;
  }
}

// ------------- convert + transpose weights: [K][N] f32 -> [N][K] bf16 -------------
__global__ void transpose_conv_kernel(const float* __restrict__ in, bf16_t* __restrict__ out,
                                      int K, int N) {
  __shared__ bf16_t tile[32][33];
  const int n0 = blockIdx.x * 32, k0 = blockIdx.y * 32;
  const int tx = threadIdx.x & 31, ty = threadIdx.x >> 5;  // 8 rows/pass
#pragma unroll
  for (int ph = 0; ph < 4; ++ph) {
    int k = ty + ph * 8;
    tile[k][tx] = (bf16_t)in[(size_t)(k0 + k) * N + n0 + tx];
  }
  __syncthreads();
#pragma unroll
  for (int ph = 0; ph < 4; ++ph) {
    int n = ty + ph * 8;
    out[(size_t)(n0 + n) * K + k0 + tx] = tile[tx][n];
  }
}

// ---------------- bf16 GEMM: C[M][N] = A[M][K] * Bt[N][K]^T ----------------
// 128x128 tile, BK=64, 4 waves (2x2), double-buffered LDS, global_load_lds w=16,
// XOR swizzle (slot ^ row&7) applied on global source + on ds_read address.
template <bool F32OUT>
__global__ __launch_bounds__(256, 2) void gemm_kernel(
    const bf16_t* __restrict__ A, const bf16_t* __restrict__ Bt,
    void* __restrict__ Cout, int M, int N, int K) {
  __shared__ bf16_t As[2][128 * 64];
  __shared__ bf16_t Bs[2][128 * 64];
  const int tid = threadIdx.x;
  const int lane = tid & 63;
  const int w = tid >> 6;
  const int wm = w >> 1, wn = w & 1;
  const int lr = lane & 15, kg = lane >> 4;
  const int bm = blockIdx.y, bn = blockIdx.x;
  const bf16_t* Ab = A + (size_t)bm * 128 * K;
  const bf16_t* Bb = Bt + (size_t)bn * 128 * K;

  f32x4 acc[4][4];
#pragma unroll
  for (int i = 0; i < 4; ++i)
#pragma unroll
    for (int j = 0; j < 4; ++j) acc[i][j] = (f32x4){0.f, 0.f, 0.f, 0.f};

  const int NKT = K >> 6;
  const int sr = tid >> 3;    // row within 32-row chunk
  const int sslot = tid & 7;  // physical 16B slot

  auto stage = [&](int buf, int kt) {
    const int k0 = kt << 6;
#pragma unroll
    for (int it = 0; it < 4; ++it) {
      int r = it * 32 + sr;
      int kofs = (sslot ^ (r & 7)) << 3;  // inverse-swizzled global source
      int lidx = (it * 256 + tid) << 3;   // linear LDS dest (elems)
      gload16(Ab + (size_t)r * K + (k0 + kofs), &As[buf][lidx]);
      gload16(Bb + (size_t)r * K + (k0 + kofs), &Bs[buf][lidx]);
    }
  };

  stage(0, 0);
  __syncthreads();

  for (int kt = 0; kt < NKT; ++kt) {
    const int buf = kt & 1;
    if (kt + 1 < NKT) stage(buf ^ 1, kt + 1);
#pragma unroll
    for (int kk = 0; kk < 2; ++kk) {
      const int slot = ((kk << 2) + kg) ^ (lr & 7);
      bf16x8 af[4], bfv[4];
#pragma unroll
      for (int mt = 0; mt < 4; ++mt) {
        int r = wm * 64 + mt * 16 + lr;
        af[mt] = *(const bf16x8*)&As[buf][(r << 6) + (slot << 3)];
      }
#pragma unroll
      for (int nt = 0; nt < 4; ++nt) {
        int r = wn * 64 + nt * 16 + lr;
        bfv[nt] = *(const bf16x8*)&Bs[buf][(r << 6) + (slot << 3)];
      }
#pragma unroll
      for (int mt = 0; mt < 4; ++mt)
#pragma unroll
        for (int nt = 0; nt < 4; ++nt)
          acc[mt][nt] = mfma16(af[mt], bfv[nt], acc[mt][nt]);
    }
    __syncthreads();
  }

  const int row0 = bm * 128 + wm * 64 + kg * 4;
  const int col0 = bn * 128 + wn * 64 + lr;
#pragma unroll
  for (int mt = 0; mt < 4; ++mt)
#pragma unroll
    for (int nt = 0; nt < 4; ++nt)
#pragma unroll
      for (int rr = 0; rr < 4; ++rr) {
        size_t idx = (size_t)(row0 + mt * 16 + rr) * N + (col0 + nt * 16);
        if constexpr (F32OUT)
          ((float*)Cout)[idx] = acc[mt][nt][rr];
        else
          ((bf16_t*)Cout)[idx] = (bf16_t)acc[mt][nt][rr];
      }
}

// ---------------- causal attention: one block per (b,h) ----------------
// qkv layout: [B*T][2304], Q at +0, K at +768, V at +1536 (col = h*64+d)
#define ATT_H 12
__global__ __launch_bounds__(256, 2) void attn_kernel(const bf16_t* __restrict__ qkv,
                                                      bf16_t* __restrict__ obuf) {
  __shared__ bf16_t Ks[128 * 72];   // row pad: 144B = 9 x 16B slots (conflict-free rotation)
  __shared__ bf16_t Vt[64 * 136];   // V transposed [d][t], 272B rows = 17 slots
  __shared__ bf16_t Ps[128 * 136];  // P bf16 [q][k2]
  const int tid = threadIdx.x, lane = tid & 63, w = tid >> 6;
  const int lr = lane & 15, kg = lane >> 4;
  const int bh = blockIdx.x;
  const int b = bh / ATT_H, h = bh % ATT_H;
  const size_t base = (size_t)b * 128 * 2304;
  const int hoff = h * 64;

  // stage K rows (vector 16B loads/stores)
#pragma unroll
  for (int it = 0; it < 4; ++it) {
    int idx = it * 256 + tid;
    int r = idx >> 3, slot = idx & 7;
    bf16x8 v = *(const bf16x8*)&qkv[base + (size_t)r * 2304 + 768 + hoff + slot * 8];
    *(bf16x8*)&Ks[r * 72 + slot * 8] = v;
  }
  // stage V transposed (coalesced global reads, scattered 2B LDS writes)
#pragma unroll 4
  for (int it = 0; it < 32; ++it) {
    int idx = it * 256 + tid;
    int t = idx >> 6, d = idx & 63;
    Vt[d * 136 + t] = qkv[base + (size_t)t * 2304 + 1536 + hoff + d];
  }
  // Q fragments direct global->reg (rows 32w..32w+31)
  const int qrow0 = w * 32;
  bf16x8 qf[2][2];
#pragma unroll
  for (int mt = 0; mt < 2; ++mt)
#pragma unroll
    for (int kk = 0; kk < 2; ++kk)
      qf[mt][kk] = *(const bf16x8*)&qkv[base + (size_t)(qrow0 + mt * 16 + lr) * 2304 + hoff +
                                        kk * 32 + kg * 8];
  __syncthreads();

  const int NT = 2 * w + 2;  // causal: n-tiles 0..2w+1 only
  f32x4 acc[2][8];
#pragma unroll
  for (int mt = 0; mt < 2; ++mt)
#pragma unroll
    for (int nt = 0; nt < 8; ++nt) acc[mt][nt] = (f32x4){0.f, 0.f, 0.f, 0.f};

#pragma unroll
  for (int nt = 0; nt < 8; ++nt) {
    if (nt < NT) {
#pragma unroll
      for (int kk = 0; kk < 2; ++kk) {
        bf16x8 kf = *(const bf16x8*)&Ks[(nt * 16 + lr) * 72 + kk * 32 + kg * 8];
        acc[0][nt] = mfma16(qf[0][kk], kf, acc[0][nt]);
        acc[1][nt] = mfma16(qf[1][kk], kf, acc[1][nt]);
      }
    }
  }

  // wave-parallel softmax: rows owned by (kg,rr); reduce across 16 col-lanes
#pragma unroll
  for (int mt = 0; mt < 2; ++mt) {
#pragma unroll
    for (int rr = 0; rr < 4; ++rr) {
      const int row = qrow0 + mt * 16 + kg * 4 + rr;
      float m = -1e30f;
#pragma unroll
      for (int nt = 0; nt < 8; ++nt) {
        if (nt < NT) {
          int col = nt * 16 + lr;
          float s = acc[mt][nt][rr] * 0.125f;
          s = (col <= row) ? s : -1e30f;
          acc[mt][nt][rr] = s;
          m = fmaxf(m, s);
        }
      }
      m = fmaxf(m, __shfl_xor(m, 1));
      m = fmaxf(m, __shfl_xor(m, 2));
      m = fmaxf(m, __shfl_xor(m, 4));
      m = fmaxf(m, __shfl_xor(m, 8));
      float ssum = 0.f;
#pragma unroll
      for (int nt = 0; nt < 8; ++nt) {
        if (nt < NT) {
          float p = __builtin_amdgcn_exp2f((acc[mt][nt][rr] - m) * 1.44269504f);
          acc[mt][nt][rr] = p;
          ssum += p;
        }
      }
      ssum += __shfl_xor(ssum, 1);
      ssum += __shfl_xor(ssum, 2);
      ssum += __shfl_xor(ssum, 4);
      ssum += __shfl_xor(ssum, 8);
      float inv = 1.0f / ssum;
#pragma unroll
      for (int nt = 0; nt < 8; ++nt) {
        if (nt < NT) Ps[row * 136 + nt * 16 + lr] = (bf16_t)(acc[mt][nt][rr] * inv);
      }
    }
  }

  // PV (same-wave LDS RAW; compiler inserts lgkmcnt waits)
  f32x4 oacc[2][4];
#pragma unroll
  for (int mt = 0; mt < 2; ++mt)
#pragma unroll
    for (int dt = 0; dt < 4; ++dt) oacc[mt][dt] = (f32x4){0.f, 0.f, 0.f, 0.f};

  const int KS = w + 1;  // causal: k2 chunks 0..w
#pragma unroll
  for (int ks = 0; ks < 4; ++ks) {
    if (ks < KS) {
      bf16x8 pa0 = *(const bf16x8*)&Ps[(qrow0 + lr) * 136 + ks * 32 + kg * 8];
      bf16x8 pa1 = *(const bf16x8*)&Ps[(qrow0 + 16 + lr) * 136 + ks * 32 + kg * 8];
#pragma unroll
      for (int dt = 0; dt < 4; ++dt) {
        bf16x8 vb = *(const bf16x8*)&Vt[(dt * 16 + lr) * 136 + ks * 32 + kg * 8];
        oacc[0][dt] = mfma16(pa0, vb, oacc[0][dt]);
        oacc[1][dt] = mfma16(pa1, vb, oacc[1][dt]);
      }
    }
  }

#pragma unroll
  for (int mt = 0; mt < 2; ++mt)
#pragma unroll
    for (int dt = 0; dt < 4; ++dt)
#pragma unroll
      for (int rr = 0; rr < 4; ++rr) {
        int t = qrow0 + mt * 16 + kg * 4 + rr;
        obuf[((size_t)b * 128 + t) * 768 + hoff + dt * 16 + lr] = (bf16_t)oacc[mt][dt][rr];
      }
}

// ---------------- launch ----------------
extern "C" void kernel_launch(void* const* d_in, const int* in_sizes, int n_in,
                              void* d_out, int out_size, void* d_ws, size_t ws_size,
                              hipStream_t stream) {
  const float* x = (const float*)d_in[0];       // [128,128,768]
  const float* w_qkv = (const float*)d_in[1];   // [768,2304]
  const float* w_proj = (const float*)d_in[2];  // [768,768]
  float* out = (float*)d_out;
  char* ws = (char*)d_ws;

  bf16_t* xb     = (bf16_t*)(ws);              // 16384*768*2   = 25,165,824
  bf16_t* wqkvt  = (bf16_t*)(ws + 25165824);   // 2304*768*2    =  3,538,944
  bf16_t* wprojt = (bf16_t*)(ws + 28704768);   // 768*768*2     =  1,179,648
  bf16_t* qkv    = (bf16_t*)(ws + 29884416);   // 16384*2304*2  = 75,497,472
  bf16_t* obuf   = (bf16_t*)(ws + 105381888);  // 16384*768*2   = 25,165,824 -> 130,547,712 total

  convert_kernel<<<dim3(12288), dim3(256), 0, stream>>>(x, xb, 3145728);
  transpose_conv_kernel<<<dim3(72, 24), dim3(256), 0, stream>>>(w_qkv, wqkvt, 768, 2304);
  transpose_conv_kernel<<<dim3(24, 24), dim3(256), 0, stream>>>(w_proj, wprojt, 768, 768);
  gemm_kernel<false><<<dim3(18, 128), dim3(256), 0, stream>>>(xb, wqkvt, (void*)qkv, 16384, 2304, 768);
  attn_kernel<<<dim3(1536), dim3(256), 0, stream>>>(qkv, obuf);
  gemm_kernel<true><<<dim3(6, 128), dim3(256), 0, stream>>>(obuf, wprojt, (void*)out, 16384, 768, 768);
}

// Round 2
// 168.907 us; speedup vs baseline: 1.0193x; 1.0193x over previous
//
#include <hip/hip_runtime.h>

typedef __bf16 bf16_t;
typedef bf16_t bf16x8 __attribute__((ext_vector_type(8)));
typedef bf16_t bf16x4 __attribute__((ext_vector_type(4)));
typedef float f32x4 __attribute__((ext_vector_type(4)));

__device__ __forceinline__ f32x4 mfma16(bf16x8 a, bf16x8 b, f32x4 c) {
  return __builtin_amdgcn_mfma_f32_16x16x32_bf16(a, b, c, 0, 0, 0);
}

__device__ __forceinline__ void gload16(const bf16_t* g, bf16_t* l) {
  __builtin_amdgcn_global_load_lds(
      (const __attribute__((address_space(1))) void*)g,
      (__attribute__((address_space(3))) void*)l, 16, 0, 0);
}

#define BARRIER()                      \
  do {                                 \
    asm volatile("" ::: "memory");     \
    __builtin_amdgcn_s_barrier();      \
    asm volatile("" ::: "memory");     \
  } while (0)
#define VMCNT(n) asm volatile("s_waitcnt vmcnt(" #n ")" ::: "memory")

// ---------------- convert f32 -> bf16 (vectorized) ----------------
__global__ void convert_kernel(const float* __restrict__ in, bf16_t* __restrict__ out, int n4) {
  int i = blockIdx.x * blockDim.x + threadIdx.x;
  if (i < n4) {
    float4 v = ((const float4*)in)[i];
    bf16x4 o;
    o[0] = (bf16_t)v.x; o[1] = (bf16_t)v.y; o[2] = (bf16_t)v.z; o[3] = (bf16_t)v.w;
    *(bf16x4*)&out[(size_t)i * 4] = o;
  }
}

// ------------- convert + transpose weights: [K][N] f32 -> [N][K] bf16 -------------
__global__ void transpose_conv_kernel(const float* __restrict__ in, bf16_t* __restrict__ out,
                                      int K, int N) {
  __shared__ bf16_t tile[32][33];
  const int n0 = blockIdx.x * 32, k0 = blockIdx.y * 32;
  const int tx = threadIdx.x & 31, ty = threadIdx.x >> 5;
#pragma unroll
  for (int ph = 0; ph < 4; ++ph) {
    int k = ty + ph * 8;
    tile[k][tx] = (bf16_t)in[(size_t)(k0 + k) * N + n0 + tx];
  }
  __syncthreads();
#pragma unroll
  for (int ph = 0; ph < 4; ++ph) {
    int n = ty + ph * 8;
    out[(size_t)(n0 + n) * K + k0 + tx] = tile[tx][n];
  }
}

// ---------------- 256x256 8-phase bf16 GEMM: C = A[M][K] * Bt[N][K]^T ----------------
// 8 waves (2M x 4N), BK=64, 128 KiB LDS (ring of 2 K-tiles per operand),
// per-phase {ds_read | 1 half-tile gload_lds} -> barrier -> setprio+16 MFMA -> barrier,
// counted vmcnt(4) at phases 4 and 8 only. XOR swizzle slot^(row&7), T1 XCD swizzle.
template <bool F32OUT>
__global__ __launch_bounds__(512, 2) void gemm8_kernel(
    const bf16_t* __restrict__ A, const bf16_t* __restrict__ Bt,
    void* __restrict__ Cout, int M, int N, int K, int nbn) {
  __shared__ bf16_t As[2][256 * 64];
  __shared__ bf16_t Bs[2][256 * 64];
  const int tid = threadIdx.x;
  const int lane = tid & 63;
  const int w = tid >> 6;
  const int wm = w >> 2, wn = w & 3;  // 2 x 4 wave grid
  const int lr = lane & 15, kg = lane >> 4;

  // XCD-aware swizzle (grid % 8 == 0 in all our launches)
  const int nwg = gridDim.x;
  const int cpx = nwg >> 3;
  const int bid = blockIdx.x;
  const int sid = (bid & 7) * cpx + (bid >> 3);
  const int bm = sid / nbn, bn = sid % nbn;

  const bf16_t* Ab = A + (size_t)bm * 256 * K;
  const bf16_t* Bb = Bt + (size_t)bn * 256 * K;

  f32x4 acc[8][4];
#pragma unroll
  for (int i = 0; i < 8; ++i)
#pragma unroll
    for (int j = 0; j < 4; ++j) acc[i][j] = (f32x4){0.f, 0.f, 0.f, 0.f};

  const int NKT = K >> 6;  // K-tiles of 64
  const int NIT = NKT >> 1;

  // stage one half-tile: part 0=A-lo,1=A-hi,2=B-lo,3=B-hi ; dest slot = tau&1
  auto stageAbs = [&](int tau, int part) {
    const int h = part & 1;
    const bf16_t* Pb = (part < 2) ? Ab : Bb;
    bf16_t* Ls = (part < 2) ? &As[tau & 1][0] : &Bs[tau & 1][0];
    const int k0 = tau << 6;
#pragma unroll
    for (int j = 0; j < 2; ++j) {
      int idx = j * 512 + tid;
      int rl = idx >> 3, p = idx & 7;
      gload16(Pb + (size_t)(h * 128 + rl) * K + (k0 + ((p ^ (rl & 7)) << 3)),
              Ls + h * 8192 + idx * 8);
    }
  };
  // stage-stream: ht g covers tile 2+g/4, part g%4 (lags compute by 2 phases)
  auto stageHT = [&](int g) {
    if (g < 0) return;
    int tau = 2 + (g >> 2);
    if (tau >= NKT) return;
    stageAbs(tau, g & 3);
  };

  auto readA = [&](int slot, int mh, bf16x8 aF[4][2]) {
#pragma unroll
    for (int mq = 0; mq < 4; ++mq) {
      int r = wm * 128 + mh * 64 + mq * 16 + lr;
#pragma unroll
      for (int kk = 0; kk < 2; ++kk) {
        int c = ((kk << 2) + kg) ^ (lr & 7);
        aF[mq][kk] = *(const bf16x8*)&As[slot][r * 64 + c * 8];
      }
    }
  };
  auto readB = [&](int slot, int nh, bf16x8 bF[2][2]) {
#pragma unroll
    for (int nq = 0; nq < 2; ++nq) {
      int r = wn * 64 + (nh * 2 + nq) * 16 + lr;
#pragma unroll
      for (int kk = 0; kk < 2; ++kk) {
        int c = ((kk << 2) + kg) ^ (lr & 7);
        bF[nq][kk] = *(const bf16x8*)&Bs[slot][r * 64 + c * 8];
      }
    }
  };
  auto quad = [&](int mh, int nh, bf16x8 aF[4][2], bf16x8 bF[2][2]) {
    __builtin_amdgcn_s_setprio(1);
#pragma unroll
    for (int mq = 0; mq < 4; ++mq)
#pragma unroll
      for (int nq = 0; nq < 2; ++nq)
#pragma unroll
        for (int kk = 0; kk < 2; ++kk)
          acc[mh * 4 + mq][nh * 2 + nq] =
              mfma16(aF[mq][kk], bF[nq][kk], acc[mh * 4 + mq][nh * 2 + nq]);
    __builtin_amdgcn_s_setprio(0);
  };

  // prologue: stage tiles 0 and 1 fully (16 loads in flight), wait tile 0 only
#pragma unroll
  for (int part = 0; part < 4; ++part) stageAbs(0, part);
#pragma unroll
  for (int part = 0; part < 4; ++part) stageAbs(1, part);
  VMCNT(8);
  BARRIER();

  bf16x8 aF0[4][2], aF1[4][2], bF[2][2];
  for (int it = 0; it < NIT; ++it) {
    const int g0 = it * 8;
    // ---- K-tile t = 2*it (slot 0) ----
    // ph1
    readA(0, 0, aF0);
    readB(0, 0, bF);
    stageHT(g0 - 2);
    BARRIER();
    quad(0, 0, aF0, bF);
    BARRIER();
    // ph2
    readA(0, 1, aF1);
    stageHT(g0 - 1);
    BARRIER();
    quad(1, 0, aF1, bF);
    BARRIER();
    // ph3
    readB(0, 1, bF);
    stageHT(g0 + 0);
    BARRIER();
    quad(1, 1, aF1, bF);
    BARRIER();
    // ph4
    stageHT(g0 + 1);
    VMCNT(4);
    BARRIER();
    quad(0, 1, aF0, bF);
    BARRIER();
    // ---- K-tile t+1 (slot 1) ----
    // ph5
    readA(1, 0, aF0);
    readB(1, 0, bF);
    stageHT(g0 + 2);
    BARRIER();
    quad(0, 0, aF0, bF);
    BARRIER();
    // ph6
    readA(1, 1, aF1);
    stageHT(g0 + 3);
    BARRIER();
    quad(1, 0, aF1, bF);
    BARRIER();
    // ph7
    readB(1, 1, bF);
    stageHT(g0 + 4);
    BARRIER();
    quad(1, 1, aF1, bF);
    BARRIER();
    // ph8
    stageHT(g0 + 5);
    VMCNT(4);
    BARRIER();
    quad(0, 1, aF0, bF);
    BARRIER();
  }

  // epilogue: C write. row = bm*256 + wm*128 + mt*16 + kg*4 + rr ; col = bn*256 + wn*64 + nt*16 + lr
  const int row0 = bm * 256 + wm * 128 + kg * 4;
  const int col0 = bn * 256 + wn * 64 + lr;
#pragma unroll
  for (int mt = 0; mt < 8; ++mt)
#pragma unroll
    for (int nt = 0; nt < 4; ++nt)
#pragma unroll
      for (int rr = 0; rr < 4; ++rr) {
        size_t idx = (size_t)(row0 + mt * 16 + rr) * N + (col0 + nt * 16);
        if constexpr (F32OUT)
          ((float*)Cout)[idx] = acc[mt][nt][rr];
        else
          ((bf16_t*)Cout)[idx] = (bf16_t)acc[mt][nt][rr];
      }
}

// ---------------- causal attention: one block per (b,h) ----------------
// qkv layout: [B*T][2304], Q at +0, K at +768, V at +1536 (col = h*64+d)
#define ATT_H 12
__global__ __launch_bounds__(256, 2) void attn_kernel(const bf16_t* __restrict__ qkv,
                                                      bf16_t* __restrict__ obuf) {
  __shared__ bf16_t Ks[128 * 72];   // row pad: 144B = 9 x 16B slots
  __shared__ bf16_t Vt[64 * 136];   // V transposed [d][t]
  __shared__ bf16_t Ps[128 * 136];  // P bf16 [q][k2]
  const int tid = threadIdx.x, lane = tid & 63, w = tid >> 6;
  const int lr = lane & 15, kg = lane >> 4;
  const int bh = blockIdx.x;
  const int b = bh / ATT_H, h = bh % ATT_H;
  const size_t base = (size_t)b * 128 * 2304;
  const int hoff = h * 64;

#pragma unroll
  for (int it = 0; it < 4; ++it) {
    int idx = it * 256 + tid;
    int r = idx >> 3, slot = idx & 7;
    bf16x8 v = *(const bf16x8*)&qkv[base + (size_t)r * 2304 + 768 + hoff + slot * 8];
    *(bf16x8*)&Ks[r * 72 + slot * 8] = v;
  }
#pragma unroll 4
  for (int it = 0; it < 32; ++it) {
    int idx = it * 256 + tid;
    int t = idx >> 6, d = idx & 63;
    Vt[d * 136 + t] = qkv[base + (size_t)t * 2304 + 1536 + hoff + d];
  }
  const int qrow0 = w * 32;
  bf16x8 qf[2][2];
#pragma unroll
  for (int mt = 0; mt < 2; ++mt)
#pragma unroll
    for (int kk = 0; kk < 2; ++kk)
      qf[mt][kk] = *(const bf16x8*)&qkv[base + (size_t)(qrow0 + mt * 16 + lr) * 2304 + hoff +
                                        kk * 32 + kg * 8];
  __syncthreads();

  const int NT = 2 * w + 2;
  f32x4 acc[2][8];
#pragma unroll
  for (int mt = 0; mt < 2; ++mt)
#pragma unroll
    for (int nt = 0; nt < 8; ++nt) acc[mt][nt] = (f32x4){0.f, 0.f, 0.f, 0.f};

#pragma unroll
  for (int nt = 0; nt < 8; ++nt) {
    if (nt < NT) {
#pragma unroll
      for (int kk = 0; kk < 2; ++kk) {
        bf16x8 kf = *(const bf16x8*)&Ks[(nt * 16 + lr) * 72 + kk * 32 + kg * 8];
        acc[0][nt] = mfma16(qf[0][kk], kf, acc[0][nt]);
        acc[1][nt] = mfma16(qf[1][kk], kf, acc[1][nt]);
      }
    }
  }

#pragma unroll
  for (int mt = 0; mt < 2; ++mt) {
#pragma unroll
    for (int rr = 0; rr < 4; ++rr) {
      const int row = qrow0 + mt * 16 + kg * 4 + rr;
      float m = -1e30f;
#pragma unroll
      for (int nt = 0; nt < 8; ++nt) {
        if (nt < NT) {
          int col = nt * 16 + lr;
          float s = acc[mt][nt][rr] * 0.125f;
          s = (col <= row) ? s : -1e30f;
          acc[mt][nt][rr] = s;
          m = fmaxf(m, s);
        }
      }
      m = fmaxf(m, __shfl_xor(m, 1));
      m = fmaxf(m, __shfl_xor(m, 2));
      m = fmaxf(m, __shfl_xor(m, 4));
      m = fmaxf(m, __shfl_xor(m, 8));
      float ssum = 0.f;
#pragma unroll
      for (int nt = 0; nt < 8; ++nt) {
        if (nt < NT) {
          float p = __builtin_amdgcn_exp2f((acc[mt][nt][rr] - m) * 1.44269504f);
          acc[mt][nt][rr] = p;
          ssum += p;
        }
      }
      ssum += __shfl_xor(ssum, 1);
      ssum += __shfl_xor(ssum, 2);
      ssum += __shfl_xor(ssum, 4);
      ssum += __shfl_xor(ssum, 8);
      float inv = 1.0f / ssum;
#pragma unroll
      for (int nt = 0; nt < 8; ++nt) {
        if (nt < NT) Ps[row * 136 + nt * 16 + lr] = (bf16_t)(acc[mt][nt][rr] * inv);
      }
    }
  }

  f32x4 oacc[2][4];
#pragma unroll
  for (int mt = 0; mt < 2; ++mt)
#pragma unroll
    for (int dt = 0; dt < 4; ++dt) oacc[mt][dt] = (f32x4){0.f, 0.f, 0.f, 0.f};

  const int KS = w + 1;
#pragma unroll
  for (int ks = 0; ks < 4; ++ks) {
    if (ks < KS) {
      bf16x8 pa0 = *(const bf16x8*)&Ps[(qrow0 + lr) * 136 + ks * 32 + kg * 8];
      bf16x8 pa1 = *(const bf16x8*)&Ps[(qrow0 + 16 + lr) * 136 + ks * 32 + kg * 8];
#pragma unroll
      for (int dt = 0; dt < 4; ++dt) {
        bf16x8 vb = *(const bf16x8*)&Vt[(dt * 16 + lr) * 136 + ks * 32 + kg * 8];
        oacc[0][dt] = mfma16(pa0, vb, oacc[0][dt]);
        oacc[1][dt] = mfma16(pa1, vb, oacc[1][dt]);
      }
    }
  }

#pragma unroll
  for (int mt = 0; mt < 2; ++mt)
#pragma unroll
    for (int dt = 0; dt < 4; ++dt)
#pragma unroll
      for (int rr = 0; rr < 4; ++rr) {
        int t = qrow0 + mt * 16 + kg * 4 + rr;
        obuf[((size_t)b * 128 + t) * 768 + hoff + dt * 16 + lr] = (bf16_t)oacc[mt][dt][rr];
      }
}

// ---------------- launch ----------------
extern "C" void kernel_launch(void* const* d_in, const int* in_sizes, int n_in,
                              void* d_out, int out_size, void* d_ws, size_t ws_size,
                              hipStream_t stream) {
  const float* x = (const float*)d_in[0];       // [128,128,768]
  const float* w_qkv = (const float*)d_in[1];   // [768,2304]
  const float* w_proj = (const float*)d_in[2];  // [768,768]
  float* out = (float*)d_out;
  char* ws = (char*)d_ws;

  bf16_t* xb     = (bf16_t*)(ws);              // 16384*768*2   = 25,165,824
  bf16_t* wqkvt  = (bf16_t*)(ws + 25165824);   // 2304*768*2    =  3,538,944
  bf16_t* wprojt = (bf16_t*)(ws + 28704768);   // 768*768*2     =  1,179,648
  bf16_t* qkv    = (bf16_t*)(ws + 29884416);   // 16384*2304*2  = 75,497,472
  bf16_t* obuf   = (bf16_t*)(ws + 105381888);  // 16384*768*2   = 25,165,824

  convert_kernel<<<dim3(12288), dim3(256), 0, stream>>>(x, xb, 3145728);
  transpose_conv_kernel<<<dim3(72, 24), dim3(256), 0, stream>>>(w_qkv, wqkvt, 768, 2304);
  transpose_conv_kernel<<<dim3(24, 24), dim3(256), 0, stream>>>(w_proj, wprojt, 768, 768);
  // GEMM1: M=16384, N=2304 -> 64 x 9 = 576 blocks (576 % 8 == 0)
  gemm8_kernel<false><<<dim3(576), dim3(512), 0, stream>>>(xb, wqkvt, (void*)qkv, 16384, 2304, 768, 9);
  attn_kernel<<<dim3(1536), dim3(256), 0, stream>>>(qkv, obuf);
  // GEMM2: M=16384, N=768 -> 64 x 3 = 192 blocks (192 % 8 == 0)
  gemm8_kernel<true><<<dim3(192), dim3(512), 0, stream>>>(obuf, wprojt, (void*)out, 16384, 768, 768, 3);
}

// Round 3
// 157.891 us; speedup vs baseline: 1.0904x; 1.0698x over previous
//
#include <hip/hip_runtime.h>

typedef __bf16 bf16_t;
typedef bf16_t bf16x8 __attribute__((ext_vector_type(8)));
typedef bf16_t bf16x4 __attribute__((ext_vector_type(4)));
typedef float f32x4 __attribute__((ext_vector_type(4)));

__device__ __forceinline__ f32x4 mfma16(bf16x8 a, bf16x8 b, f32x4 c) {
  return __builtin_amdgcn_mfma_f32_16x16x32_bf16(a, b, c, 0, 0, 0);
}

__device__ __forceinline__ void gload16(const bf16_t* g, bf16_t* l) {
  __builtin_amdgcn_global_load_lds(
      (const __attribute__((address_space(1))) void*)g,
      (__attribute__((address_space(3))) void*)l, 16, 0, 0);
}

// ------- merged prep: x f32->bf16 convert + both weight transposes -------
// blocks [0,12288): convert x (float4 per thread)
// blocks [12288, 12288+2304): 32x32 transpose tiles; tx<72 -> w_qkv, else w_proj
__global__ void prep_kernel(const float* __restrict__ x, const float* __restrict__ wq,
                            const float* __restrict__ wp, bf16_t* __restrict__ xb,
                            bf16_t* __restrict__ wqt, bf16_t* __restrict__ wpt) {
  __shared__ bf16_t tile[32][33];
  const int bid = blockIdx.x;
  if (bid < 12288) {
    int i = bid * 256 + threadIdx.x;
    float4 v = ((const float4*)x)[i];
    bf16x4 o;
    o[0] = (bf16_t)v.x; o[1] = (bf16_t)v.y; o[2] = (bf16_t)v.z; o[3] = (bf16_t)v.w;
    *(bf16x4*)&xb[(size_t)i * 4] = o;
    return;
  }
  const int t = bid - 12288;
  const int ty = t / 96, txb = t % 96;
  const float* in;
  bf16_t* out;
  int N, n0;
  if (txb < 72) { in = wq; out = wqt; N = 2304; n0 = txb * 32; }
  else          { in = wp; out = wpt; N = 768;  n0 = (txb - 72) * 32; }
  const int k0 = ty * 32;
  const int tx = threadIdx.x & 31, tyy = threadIdx.x >> 5;
#pragma unroll
  for (int ph = 0; ph < 4; ++ph) {
    int k = tyy + ph * 8;
    tile[k][tx] = (bf16_t)in[(size_t)(k0 + k) * N + n0 + tx];
  }
  __syncthreads();
#pragma unroll
  for (int ph = 0; ph < 4; ++ph) {
    int n = tyy + ph * 8;
    out[(size_t)(n0 + n) * 768 + k0 + tx] = tile[tx][n];
  }
}

// ---------------- persistent 128xBN bf16 GEMM: C = A[M][K] * Bt[N][K]^T ----------------
// m97-style: BK=64, 4 waves (2x2), dbuf LDS, global_load_lds w=16, XOR swizzle slot^(r&7).
// Persistent job loop (bm-major jobs -> A-panel reuse), XCD-chunked block remap,
// next job's tile0 prefetched during current job's last K-step.
template <int BN, bool F32OUT>
__global__ __launch_bounds__(256, 3) void gemm_persist(
    const bf16_t* __restrict__ A, const bf16_t* __restrict__ Bt,
    void* __restrict__ Cout, int N, int K, int nbn, int q, int r) {
  constexpr int NQ = BN / 32;  // B n-quadrants per wave
  __shared__ bf16_t As[2][128 * 64];
  __shared__ bf16_t Bs[2][BN * 64];
  const int tid = threadIdx.x;
  const int lane = tid & 63;
  const int w = tid >> 6;
  const int wm = w >> 1, wn = w & 1;
  const int lr = lane & 15, kg = lane >> 4;

  // XCD-chunked remap: physical XCD ~ bid%8; give each XCD a contiguous job window
  const int G = gridDim.x;
  const int bid = blockIdx.x;
  const int lb = (bid & 7) * (G >> 3) + (bid >> 3);
  int nj, start;
  if (lb < r) { nj = q + 1; start = lb * (q + 1); }
  else        { nj = q;     start = r * (q + 1) + (lb - r) * q; }

  const int NKT = K >> 6;
  const int sr = tid >> 3, sslot = tid & 7;

  auto stage = [&](int buf, const bf16_t* Aj, const bf16_t* Bj, int k0) {
#pragma unroll
    for (int it = 0; it < 4; ++it) {
      int rr = it * 32 + sr;
      gload16(Aj + (size_t)rr * K + (k0 + ((sslot ^ (rr & 7)) << 3)),
              &As[buf][(it * 256 + tid) * 8]);
    }
#pragma unroll
    for (int it = 0; it < NQ; ++it) {
      int rr = it * 32 + sr;
      gload16(Bj + (size_t)rr * K + (k0 + ((sslot ^ (rr & 7)) << 3)),
              &Bs[buf][(it * 256 + tid) * 8]);
    }
  };

  int job = start;
  int bm = job / nbn, bn = job % nbn;
  const bf16_t* Aj = A + (size_t)bm * 128 * K;
  const bf16_t* Bj = Bt + (size_t)bn * BN * K;
  stage(0, Aj, Bj, 0);
  __syncthreads();
  int buf = 0;

  for (int j = 0; j < nj; ++j) {
    f32x4 acc[4][NQ];
#pragma unroll
    for (int i = 0; i < 4; ++i)
#pragma unroll
      for (int n = 0; n < NQ; ++n) acc[i][n] = (f32x4){0.f, 0.f, 0.f, 0.f};

    // next job pointers (for cross-job prefetch)
    int nbm = 0, nbnx = 0;
    const bf16_t *nAj = nullptr, *nBj = nullptr;
    if (j + 1 < nj) {
      int njob = job + 1;
      nbm = njob / nbn; nbnx = njob % nbn;
      nAj = A + (size_t)nbm * 128 * K;
      nBj = Bt + (size_t)nbnx * BN * K;
    }

    for (int kt = 0; kt < NKT; ++kt) {
      if (kt + 1 < NKT)      stage(buf ^ 1, Aj, Bj, (kt + 1) << 6);
      else if (j + 1 < nj)   stage(buf ^ 1, nAj, nBj, 0);
#pragma unroll
      for (int kk = 0; kk < 2; ++kk) {
        const int slot = ((kk << 2) + kg) ^ (lr & 7);
        bf16x8 af[4], bfv[NQ];
#pragma unroll
        for (int mq = 0; mq < 4; ++mq) {
          int rr = wm * 64 + mq * 16 + lr;
          af[mq] = *(const bf16x8*)&As[buf][(rr << 6) + (slot << 3)];
        }
#pragma unroll
        for (int nq = 0; nq < NQ; ++nq) {
          int rr = wn * (BN / 2) + nq * 16 + lr;
          bfv[nq] = *(const bf16x8*)&Bs[buf][(rr << 6) + (slot << 3)];
        }
#pragma unroll
        for (int mq = 0; mq < 4; ++mq)
#pragma unroll
          for (int nq = 0; nq < NQ; ++nq)
            acc[mq][nq] = mfma16(af[mq], bfv[nq], acc[mq][nq]);
      }
      __syncthreads();
      buf ^= 1;
    }

    // epilogue (overlaps next job's staged loads; drained at next sync)
    const int row0 = bm * 128 + wm * 64 + kg * 4;
    const int col0 = bn * BN + wn * (BN / 2) + lr;
#pragma unroll
    for (int mq = 0; mq < 4; ++mq)
#pragma unroll
      for (int nq = 0; nq < NQ; ++nq)
#pragma unroll
        for (int rr = 0; rr < 4; ++rr) {
          size_t idx = (size_t)(row0 + mq * 16 + rr) * N + (col0 + nq * 16);
          if constexpr (F32OUT)
            ((float*)Cout)[idx] = acc[mq][nq][rr];
          else
            ((bf16_t*)Cout)[idx] = (bf16_t)acc[mq][nq][rr];
        }

    job++; bm = nbm; bn = nbnx; Aj = nAj; Bj = nBj;
  }
}

// ---------------- causal attention: one block per (b,h) ----------------
// qkv layout: [B*T][2304], Q at +0, K at +768, V at +1536 (col = h*64+d)
#define ATT_H 12
__global__ __launch_bounds__(256, 2) void attn_kernel(const bf16_t* __restrict__ qkv,
                                                      bf16_t* __restrict__ obuf) {
  __shared__ bf16_t Ks[128 * 72];   // row pad: 144B = 9 x 16B slots
  __shared__ bf16_t Vt[64 * 136];   // V transposed [d][t]
  __shared__ bf16_t Ps[128 * 136];  // P bf16 [q][k2]
  const int tid = threadIdx.x, lane = tid & 63, w = tid >> 6;
  const int lr = lane & 15, kg = lane >> 4;
  const int bh = blockIdx.x;
  const int b = bh / ATT_H, h = bh % ATT_H;
  const size_t base = (size_t)b * 128 * 2304;
  const int hoff = h * 64;

#pragma unroll
  for (int it = 0; it < 4; ++it) {
    int idx = it * 256 + tid;
    int r = idx >> 3, slot = idx & 7;
    bf16x8 v = *(const bf16x8*)&qkv[base + (size_t)r * 2304 + 768 + hoff + slot * 8];
    *(bf16x8*)&Ks[r * 72 + slot * 8] = v;
  }
#pragma unroll 4
  for (int it = 0; it < 32; ++it) {
    int idx = it * 256 + tid;
    int t = idx >> 6, d = idx & 63;
    Vt[d * 136 + t] = qkv[base + (size_t)t * 2304 + 1536 + hoff + d];
  }
  const int qrow0 = w * 32;
  bf16x8 qf[2][2];
#pragma unroll
  for (int mt = 0; mt < 2; ++mt)
#pragma unroll
    for (int kk = 0; kk < 2; ++kk)
      qf[mt][kk] = *(const bf16x8*)&qkv[base + (size_t)(qrow0 + mt * 16 + lr) * 2304 + hoff +
                                        kk * 32 + kg * 8];
  __syncthreads();

  const int NT = 2 * w + 2;
  f32x4 acc[2][8];
#pragma unroll
  for (int mt = 0; mt < 2; ++mt)
#pragma unroll
    for (int nt = 0; nt < 8; ++nt) acc[mt][nt] = (f32x4){0.f, 0.f, 0.f, 0.f};

#pragma unroll
  for (int nt = 0; nt < 8; ++nt) {
    if (nt < NT) {
#pragma unroll
      for (int kk = 0; kk < 2; ++kk) {
        bf16x8 kf = *(const bf16x8*)&Ks[(nt * 16 + lr) * 72 + kk * 32 + kg * 8];
        acc[0][nt] = mfma16(qf[0][kk], kf, acc[0][nt]);
        acc[1][nt] = mfma16(qf[1][kk], kf, acc[1][nt]);
      }
    }
  }

#pragma unroll
  for (int mt = 0; mt < 2; ++mt) {
#pragma unroll
    for (int rr = 0; rr < 4; ++rr) {
      const int row = qrow0 + mt * 16 + kg * 4 + rr;
      float m = -1e30f;
#pragma unroll
      for (int nt = 0; nt < 8; ++nt) {
        if (nt < NT) {
          int col = nt * 16 + lr;
          float s = acc[mt][nt][rr] * 0.125f;
          s = (col <= row) ? s : -1e30f;
          acc[mt][nt][rr] = s;
          m = fmaxf(m, s);
        }
      }
      m = fmaxf(m, __shfl_xor(m, 1));
      m = fmaxf(m, __shfl_xor(m, 2));
      m = fmaxf(m, __shfl_xor(m, 4));
      m = fmaxf(m, __shfl_xor(m, 8));
      float ssum = 0.f;
#pragma unroll
      for (int nt = 0; nt < 8; ++nt) {
        if (nt < NT) {
          float p = __builtin_amdgcn_exp2f((acc[mt][nt][rr] - m) * 1.44269504f);
          acc[mt][nt][rr] = p;
          ssum += p;
        }
      }
      ssum += __shfl_xor(ssum, 1);
      ssum += __shfl_xor(ssum, 2);
      ssum += __shfl_xor(ssum, 4);
      ssum += __shfl_xor(ssum, 8);
      float inv = 1.0f / ssum;
#pragma unroll
      for (int nt = 0; nt < 8; ++nt) {
        if (nt < NT) Ps[row * 136 + nt * 16 + lr] = (bf16_t)(acc[mt][nt][rr] * inv);
      }
    }
  }

  f32x4 oacc[2][4];
#pragma unroll
  for (int mt = 0; mt < 2; ++mt)
#pragma unroll
    for (int dt = 0; dt < 4; ++dt) oacc[mt][dt] = (f32x4){0.f, 0.f, 0.f, 0.f};

  const int KS = w + 1;
#pragma unroll
  for (int ks = 0; ks < 4; ++ks) {
    if (ks < KS) {
      bf16x8 pa0 = *(const bf16x8*)&Ps[(qrow0 + lr) * 136 + ks * 32 + kg * 8];
      bf16x8 pa1 = *(const bf16x8*)&Ps[(qrow0 + 16 + lr) * 136 + ks * 32 + kg * 8];
#pragma unroll
      for (int dt = 0; dt < 4; ++dt) {
        bf16x8 vb = *(const bf16x8*)&Vt[(dt * 16 + lr) * 136 + ks * 32 + kg * 8];
        oacc[0][dt] = mfma16(pa0, vb, oacc[0][dt]);
        oacc[1][dt] = mfma16(pa1, vb, oacc[1][dt]);
      }
    }
  }

#pragma unroll
  for (int mt = 0; mt < 2; ++mt)
#pragma unroll
    for (int dt = 0; dt < 4; ++dt)
#pragma unroll
      for (int rr = 0; rr < 4; ++rr) {
        int t = qrow0 + mt * 16 + kg * 4 + rr;
        obuf[((size_t)b * 128 + t) * 768 + hoff + dt * 16 + lr] = (bf16_t)oacc[mt][dt][rr];
      }
}

// ---------------- launch ----------------
extern "C" void kernel_launch(void* const* d_in, const int* in_sizes, int n_in,
                              void* d_out, int out_size, void* d_ws, size_t ws_size,
                              hipStream_t stream) {
  const float* x = (const float*)d_in[0];       // [128,128,768]
  const float* w_qkv = (const float*)d_in[1];   // [768,2304]
  const float* w_proj = (const float*)d_in[2];  // [768,768]
  float* out = (float*)d_out;
  char* ws = (char*)d_ws;

  bf16_t* xb     = (bf16_t*)(ws);              // 16384*768*2   = 25,165,824
  bf16_t* wqkvt  = (bf16_t*)(ws + 25165824);   // 2304*768*2    =  3,538,944
  bf16_t* wprojt = (bf16_t*)(ws + 28704768);   // 768*768*2     =  1,179,648
  bf16_t* qkv    = (bf16_t*)(ws + 29884416);   // 16384*2304*2  = 75,497,472
  bf16_t* obuf   = (bf16_t*)(ws + 105381888);  // 16384*768*2   = 25,165,824

  // prep: 12288 convert blocks + 96*24 = 2304 transpose blocks
  prep_kernel<<<dim3(12288 + 2304), dim3(256), 0, stream>>>(x, w_qkv, w_proj, xb, wqkvt, wprojt);
  // GEMM1: M=16384 N=2304 K=768; jobs = 128*18 = 2304; grid 512 (2/CU): q=4, r=256
  gemm_persist<128, false><<<dim3(512), dim3(256), 0, stream>>>(
      xb, wqkvt, (void*)qkv, 2304, 768, 18, 4, 256);
  attn_kernel<<<dim3(1536), dim3(256), 0, stream>>>(qkv, obuf);
  // GEMM2: M=16384 N=768 K=768, BN=64; jobs = 128*12 = 1536; grid 768 (3/CU): q=2, r=0
  gemm_persist<64, true><<<dim3(768), dim3(256), 0, stream>>>(
      obuf, wprojt, (void*)out, 768, 768, 12, 2, 0);
}

// Round 4
// 157.230 us; speedup vs baseline: 1.0950x; 1.0042x over previous
//
#include <hip/hip_runtime.h>

typedef __bf16 bf16_t;
typedef bf16_t bf16x8 __attribute__((ext_vector_type(8)));
typedef bf16_t bf16x4 __attribute__((ext_vector_type(4)));
typedef float f32x4 __attribute__((ext_vector_type(4)));

__device__ __forceinline__ f32x4 mfma16(bf16x8 a, bf16x8 b, f32x4 c) {
  return __builtin_amdgcn_mfma_f32_16x16x32_bf16(a, b, c, 0, 0, 0);
}

__device__ __forceinline__ void gload16(const bf16_t* g, bf16_t* l) {
  __builtin_amdgcn_global_load_lds(
      (const __attribute__((address_space(1))) void*)g,
      (__attribute__((address_space(3))) void*)l, 16, 0, 0);
}

#define BARRIER()                      \
  do {                                 \
    asm volatile("" ::: "memory");     \
    __builtin_amdgcn_s_barrier();      \
    asm volatile("" ::: "memory");     \
  } while (0)
#define VMCNT(n) asm volatile("s_waitcnt vmcnt(" #n ")" ::: "memory")

// ------- merged prep: x f32->bf16 convert + both weight transposes -------
__global__ void prep_kernel(const float* __restrict__ x, const float* __restrict__ wq,
                            const float* __restrict__ wp, bf16_t* __restrict__ xb,
                            bf16_t* __restrict__ wqt, bf16_t* __restrict__ wpt) {
  __shared__ bf16_t tile[32][33];
  const int bid = blockIdx.x;
  if (bid < 12288) {
    int i = bid * 256 + threadIdx.x;
    float4 v = ((const float4*)x)[i];
    bf16x4 o;
    o[0] = (bf16_t)v.x; o[1] = (bf16_t)v.y; o[2] = (bf16_t)v.z; o[3] = (bf16_t)v.w;
    *(bf16x4*)&xb[(size_t)i * 4] = o;
    return;
  }
  const int t = bid - 12288;
  const int ty = t / 96, txb = t % 96;
  const float* in;
  bf16_t* out;
  int N, n0;
  if (txb < 72) { in = wq; out = wqt; N = 2304; n0 = txb * 32; }
  else          { in = wp; out = wpt; N = 768;  n0 = (txb - 72) * 32; }
  const int k0 = ty * 32;
  const int tx = threadIdx.x & 31, tyy = threadIdx.x >> 5;
#pragma unroll
  for (int ph = 0; ph < 4; ++ph) {
    int k = tyy + ph * 8;
    tile[k][tx] = (bf16_t)in[(size_t)(k0 + k) * N + n0 + tx];
  }
  __syncthreads();
#pragma unroll
  for (int ph = 0; ph < 4; ++ph) {
    int n = tyy + ph * 8;
    out[(size_t)(n0 + n) * 768 + k0 + tx] = tile[tx][n];
  }
}

// ------- persistent 128x64 bf16 GEMM, 3-deep LDS ring + counted vmcnt -------
// C = A[M][768] * Bt[N][768]^T. 4 waves (2x2), wave tile 64x32. Ring slot = kt%3.
// Per K-step: VMCNT(6) -> s_barrier -> stage(kt+2) -> ds_read+MFMA. Never vmcnt(0)
// in steady state (T4). Jobs per block are consecutive bn within one constant bm.
template <bool F32OUT>
__global__ __launch_bounds__(256, 2) void gemm_ring(
    const bf16_t* __restrict__ A, const bf16_t* __restrict__ Bt,
    void* __restrict__ Cout, int N, int nbn, int jpb) {
  constexpr int K = 768;
  constexpr int NKT = 12;  // K / 64
  __shared__ bf16_t ring[3][12288];  // per slot: A 128x64 @0, B 64x64 @8192
  const int tid = threadIdx.x;
  const int lane = tid & 63;
  const int w = tid >> 6;
  const int wm = w >> 1, wn = w & 1;
  const int lr = lane & 15, kg = lane >> 4;

  // XCD-chunked remap
  const int G = gridDim.x;
  const int bid = blockIdx.x;
  const int lb = (bid & 7) * (G >> 3) + (bid >> 3);
  const int start = lb * jpb;
  const int bm = start / nbn;   // constant per block (jpb divides nbn)
  const int bn0 = start % nbn;
  const bf16_t* Ab = A + (size_t)bm * 128 * K;
  const int S = jpb * NKT;      // total stage count for this block

  auto stageS = [&](int s) {
    if (s >= S) return;
    const int jb = s / NKT;
    const int kt = s - jb * NKT;
    const int k0 = kt << 6;
    const bf16_t* Bj = Bt + (size_t)(bn0 + jb) * 64 * K;
    bf16_t* L = &ring[kt % 3][0];
#pragma unroll
    for (int it = 0; it < 4; ++it) {
      int c = it * 256 + tid;
      int r = c >> 3, p = c & 7;
      gload16(Ab + (size_t)r * K + (k0 + ((p ^ (r & 7)) << 3)), L + c * 8);
    }
#pragma unroll
    for (int it = 0; it < 2; ++it) {
      int c = it * 256 + tid;
      int r = c >> 3, p = c & 7;
      gload16(Bj + (size_t)r * K + (k0 + ((p ^ (r & 7)) << 3)), L + 8192 + c * 8);
    }
  };

  // prologue: stages 0,1 in flight
  stageS(0);
  stageS(1);

  for (int j = 0; j < jpb; ++j) {
    f32x4 acc[4][2];
#pragma unroll
    for (int i = 0; i < 4; ++i)
#pragma unroll
      for (int n = 0; n < 2; ++n) acc[i][n] = (f32x4){0.f, 0.f, 0.f, 0.f};

    const int sbase = j * NKT;
    const bool lastj = (j == jpb - 1);

    for (int kt = 0; kt < NKT; ++kt) {
      // ensure stage(kt) landed: one stage (kt+1) in flight beyond it -> 6;
      // at the very last tile nothing is beyond -> 0.
      if (lastj && kt == NKT - 1) { VMCNT(0); } else { VMCNT(6); }
      BARRIER();  // all waves: tile kt ready; slot (kt+2)%3 free
      stageS(sbase + kt + 2);

      const bf16_t* L = &ring[kt % 3][0];
#pragma unroll
      for (int kk = 0; kk < 2; ++kk) {
        const int q = (kk << 2) + kg;
        const int ph = q ^ (lr & 7);
        bf16x8 af[4], bfv[2];
#pragma unroll
        for (int mq = 0; mq < 4; ++mq) {
          int r = wm * 64 + mq * 16 + lr;
          af[mq] = *(const bf16x8*)&L[r * 64 + ph * 8];
        }
#pragma unroll
        for (int nq = 0; nq < 2; ++nq) {
          int r = wn * 32 + nq * 16 + lr;
          bfv[nq] = *(const bf16x8*)&L[8192 + r * 64 + ph * 8];
        }
#pragma unroll
        for (int mq = 0; mq < 4; ++mq)
#pragma unroll
          for (int nq = 0; nq < 2; ++nq)
            acc[mq][nq] = mfma16(af[mq], bfv[nq], acc[mq][nq]);
      }
    }

    // C write (overlaps next job's in-flight stages; next VMCNT drains stores)
    const int bn = bn0 + j;
    const int row0 = bm * 128 + wm * 64 + kg * 4;
    const int col0 = bn * 64 + wn * 32 + lr;
#pragma unroll
    for (int mq = 0; mq < 4; ++mq)
#pragma unroll
      for (int nq = 0; nq < 2; ++nq)
#pragma unroll
        for (int rr = 0; rr < 4; ++rr) {
          size_t idx = (size_t)(row0 + mq * 16 + rr) * N + (col0 + nq * 16);
          if constexpr (F32OUT)
            ((float*)Cout)[idx] = acc[mq][nq][rr];
          else
            ((bf16_t*)Cout)[idx] = (bf16_t)acc[mq][nq][rr];
        }
  }
}

// ---------------- causal attention: one block per (b,h) ----------------
#define ATT_H 12
__global__ __launch_bounds__(256, 2) void attn_kernel(const bf16_t* __restrict__ qkv,
                                                      bf16_t* __restrict__ obuf) {
  __shared__ bf16_t Ks[128 * 72];
  __shared__ bf16_t Vt[64 * 136];
  __shared__ bf16_t Ps[128 * 136];
  const int tid = threadIdx.x, lane = tid & 63, w = tid >> 6;
  const int lr = lane & 15, kg = lane >> 4;
  const int bh = blockIdx.x;
  const int b = bh / ATT_H, h = bh % ATT_H;
  const size_t base = (size_t)b * 128 * 2304;
  const int hoff = h * 64;

#pragma unroll
  for (int it = 0; it < 4; ++it) {
    int idx = it * 256 + tid;
    int r = idx >> 3, slot = idx & 7;
    bf16x8 v = *(const bf16x8*)&qkv[base + (size_t)r * 2304 + 768 + hoff + slot * 8];
    *(bf16x8*)&Ks[r * 72 + slot * 8] = v;
  }
#pragma unroll 4
  for (int it = 0; it < 32; ++it) {
    int idx = it * 256 + tid;
    int t = idx >> 6, d = idx & 63;
    Vt[d * 136 + t] = qkv[base + (size_t)t * 2304 + 1536 + hoff + d];
  }
  const int qrow0 = w * 32;
  bf16x8 qf[2][2];
#pragma unroll
  for (int mt = 0; mt < 2; ++mt)
#pragma unroll
    for (int kk = 0; kk < 2; ++kk)
      qf[mt][kk] = *(const bf16x8*)&qkv[base + (size_t)(qrow0 + mt * 16 + lr) * 2304 + hoff +
                                        kk * 32 + kg * 8];
  __syncthreads();

  const int NT = 2 * w + 2;
  f32x4 acc[2][8];
#pragma unroll
  for (int mt = 0; mt < 2; ++mt)
#pragma unroll
    for (int nt = 0; nt < 8; ++nt) acc[mt][nt] = (f32x4){0.f, 0.f, 0.f, 0.f};

#pragma unroll
  for (int nt = 0; nt < 8; ++nt) {
    if (nt < NT) {
#pragma unroll
      for (int kk = 0; kk < 2; ++kk) {
        bf16x8 kf = *(const bf16x8*)&Ks[(nt * 16 + lr) * 72 + kk * 32 + kg * 8];
        acc[0][nt] = mfma16(qf[0][kk], kf, acc[0][nt]);
        acc[1][nt] = mfma16(qf[1][kk], kf, acc[1][nt]);
      }
    }
  }

#pragma unroll
  for (int mt = 0; mt < 2; ++mt) {
#pragma unroll
    for (int rr = 0; rr < 4; ++rr) {
      const int row = qrow0 + mt * 16 + kg * 4 + rr;
      float m = -1e30f;
#pragma unroll
      for (int nt = 0; nt < 8; ++nt) {
        if (nt < NT) {
          int col = nt * 16 + lr;
          float s = acc[mt][nt][rr] * 0.125f;
          s = (col <= row) ? s : -1e30f;
          acc[mt][nt][rr] = s;
          m = fmaxf(m, s);
        }
      }
      m = fmaxf(m, __shfl_xor(m, 1));
      m = fmaxf(m, __shfl_xor(m, 2));
      m = fmaxf(m, __shfl_xor(m, 4));
      m = fmaxf(m, __shfl_xor(m, 8));
      float ssum = 0.f;
#pragma unroll
      for (int nt = 0; nt < 8; ++nt) {
        if (nt < NT) {
          float p = __builtin_amdgcn_exp2f((acc[mt][nt][rr] - m) * 1.44269504f);
          acc[mt][nt][rr] = p;
          ssum += p;
        }
      }
      ssum += __shfl_xor(ssum, 1);
      ssum += __shfl_xor(ssum, 2);
      ssum += __shfl_xor(ssum, 4);
      ssum += __shfl_xor(ssum, 8);
      float inv = 1.0f / ssum;
#pragma unroll
      for (int nt = 0; nt < 8; ++nt) {
        if (nt < NT) Ps[row * 136 + nt * 16 + lr] = (bf16_t)(acc[mt][nt][rr] * inv);
      }
    }
  }

  f32x4 oacc[2][4];
#pragma unroll
  for (int mt = 0; mt < 2; ++mt)
#pragma unroll
    for (int dt = 0; dt < 4; ++dt) oacc[mt][dt] = (f32x4){0.f, 0.f, 0.f, 0.f};

  const int KS = w + 1;
#pragma unroll
  for (int ks = 0; ks < 4; ++ks) {
    if (ks < KS) {
      bf16x8 pa0 = *(const bf16x8*)&Ps[(qrow0 + lr) * 136 + ks * 32 + kg * 8];
      bf16x8 pa1 = *(const bf16x8*)&Ps[(qrow0 + 16 + lr) * 136 + ks * 32 + kg * 8];
#pragma unroll
      for (int dt = 0; dt < 4; ++dt) {
        bf16x8 vb = *(const bf16x8*)&Vt[(dt * 16 + lr) * 136 + ks * 32 + kg * 8];
        oacc[0][dt] = mfma16(pa0, vb, oacc[0][dt]);
        oacc[1][dt] = mfma16(pa1, vb, oacc[1][dt]);
      }
    }
  }

#pragma unroll
  for (int mt = 0; mt < 2; ++mt)
#pragma unroll
    for (int dt = 0; dt < 4; ++dt)
#pragma unroll
      for (int rr = 0; rr < 4; ++rr) {
        int t = qrow0 + mt * 16 + kg * 4 + rr;
        obuf[((size_t)b * 128 + t) * 768 + hoff + dt * 16 + lr] = (bf16_t)oacc[mt][dt][rr];
      }
}

// ---------------- launch ----------------
extern "C" void kernel_launch(void* const* d_in, const int* in_sizes, int n_in,
                              void* d_out, int out_size, void* d_ws, size_t ws_size,
                              hipStream_t stream) {
  const float* x = (const float*)d_in[0];       // [128,128,768]
  const float* w_qkv = (const float*)d_in[1];   // [768,2304]
  const float* w_proj = (const float*)d_in[2];  // [768,768]
  float* out = (float*)d_out;
  char* ws = (char*)d_ws;

  bf16_t* xb     = (bf16_t*)(ws);              // 16384*768*2   = 25,165,824
  bf16_t* wqkvt  = (bf16_t*)(ws + 25165824);   // 2304*768*2    =  3,538,944
  bf16_t* wprojt = (bf16_t*)(ws + 28704768);   // 768*768*2     =  1,179,648
  bf16_t* qkv    = (bf16_t*)(ws + 29884416);   // 16384*2304*2  = 75,497,472
  bf16_t* obuf   = (bf16_t*)(ws + 105381888);  // 16384*768*2   = 25,165,824

  prep_kernel<<<dim3(12288 + 2304), dim3(256), 0, stream>>>(x, w_qkv, w_proj, xb, wqkvt, wprojt);
  // GEMM1: jobs = 128 bm x 36 bn = 4608 = 512 blocks x 9 jobs (exact)
  gemm_ring<false><<<dim3(512), dim3(256), 0, stream>>>(xb, wqkvt, (void*)qkv, 2304, 36, 9);
  attn_kernel<<<dim3(1536), dim3(256), 0, stream>>>(qkv, obuf);
  // GEMM2: jobs = 128 bm x 12 bn = 1536 = 512 blocks x 3 jobs (exact)
  gemm_ring<true><<<dim3(512), dim3(256), 0, stream>>>(obuf, wprojt, (void*)out, 768, 12, 3);
}